// Round 2
// baseline (274.411 us; speedup 1.0000x reference)
//
#include <hip/hip_runtime.h>

// NetVladCNN: B=64, D=512, H=W=32 (N=1024), K=64
// All GEMM kernels: NO LDS, NO barriers. HBM floor is ~10 B/cyc/CU, so MFMA
// fragments are built directly from coalesced global loads in registers.
// K1a: feat[b][k][n] = sum_d w[k][d]*x[b][d][n]   (f32 logits -> ws)
// K1b: softmax over H (n = h*32+w, reduce over h)  -> a bf16
// K2 : V[k][d] = sum_n a[k][n]*x[d][n] - 32*c[k][d]; L2-normalize over k -> yw (B,K,D)
// K3 : transpose -> out (D,K,B)

typedef __attribute__((ext_vector_type(8))) short short8;
typedef __attribute__((ext_vector_type(4))) float f32x4;
typedef unsigned short u16;
typedef unsigned int u32;

union S8u { u32 q[4]; short8 s; };

__device__ __forceinline__ u32 pk2(float lo, float hi) {  // RNE bf16 pair pack
  union { float f; u32 u; } a, b; a.f = lo; b.f = hi;
  u32 xl = (a.u + 0x7fffu + ((a.u >> 16) & 1u)) >> 16;
  u32 xh = (b.u + 0x7fffu + ((b.u >> 16) & 1u)) & 0xffff0000u;
  return xl | xh;
}

__device__ __forceinline__ u16 bf1(float f) {
  union { float f; u32 u; } a; a.f = f;
  return (u16)((a.u + 0x7fffu + ((a.u >> 16) & 1u)) >> 16);
}

// ---------------- K1a: features GEMM (no LDS) ----------------
// grid 512 = (ntile 8)*(b 64); block 256 = 4 waves; wave: 64k x 32n, Kdim=512.
__global__ __launch_bounds__(256, 2) void k1_features(
    const float* __restrict__ x, const float* __restrict__ wgt,
    float* __restrict__ feat)
{
  const int blk = blockIdx.x;
  const int b = blk & 63, ntile = blk >> 6;   // XCD = b%8
  const int tid = threadIdx.x, lane = tid & 63, wv = tid >> 6;
  const int row = lane & 15, q = lane >> 4;
  const int nb = ntile * 128 + wv * 32;
  const float* xb = x + ((size_t)b << 19);

  f32x4 acc[4][2];
#pragma unroll
  for (int mt = 0; mt < 4; mt++)
#pragma unroll
    for (int nt = 0; nt < 2; nt++) acc[mt][nt] = (f32x4){0.f, 0.f, 0.f, 0.f};

#pragma unroll 2
  for (int d0 = 0; d0 < 512; d0 += 32) {
    short8 af[4];
#pragma unroll
    for (int mt = 0; mt < 4; mt++) {           // A: w[mt*16+row][d0+q*8 ..+7]
      const float* pw = wgt + (mt * 16 + row) * 512 + d0 + q * 8;
      f32x4 w0 = *(const f32x4*)pw;
      f32x4 w1 = *(const f32x4*)(pw + 4);
      S8u t;
      t.q[0] = pk2(w0[0], w0[1]); t.q[1] = pk2(w0[2], w0[3]);
      t.q[2] = pk2(w1[0], w1[1]); t.q[3] = pk2(w1[2], w1[3]);
      af[mt] = t.s;
    }
    short8 bf[2];
#pragma unroll
    for (int nt = 0; nt < 2; nt++) {           // B: x[d0+q*8+j][n], j=0..7 dword gathers
      const float* px = xb + (size_t)(d0 + q * 8) * 1024 + nb + nt * 16 + row;
      float v0 = px[0],    v1 = px[1024], v2 = px[2048], v3 = px[3072];
      float v4 = px[4096], v5 = px[5120], v6 = px[6144], v7 = px[7168];
      S8u t;
      t.q[0] = pk2(v0, v1); t.q[1] = pk2(v2, v3);
      t.q[2] = pk2(v4, v5); t.q[3] = pk2(v6, v7);
      bf[nt] = t.s;
    }
#pragma unroll
    for (int nt = 0; nt < 2; nt++)
#pragma unroll
      for (int mt = 0; mt < 4; mt++)
        acc[mt][nt] = __builtin_amdgcn_mfma_f32_16x16x32_bf16(af[mt], bf[nt], acc[mt][nt], 0, 0, 0);
  }
  float* fb = feat + ((size_t)b << 16);
#pragma unroll
  for (int mt = 0; mt < 4; mt++)
#pragma unroll
    for (int nt = 0; nt < 2; nt++)
#pragma unroll
      for (int r = 0; r < 4; r++)   // C layout: col=lane&15, row=q*4+r
        fb[(mt * 16 + q * 4 + r) * 1024 + nb + nt * 16 + row] = acc[mt][nt][r];
}

// ---------------- K1b: softmax over H ----------------
// grid 1024, block 256 = 4 waves; wave handles one (b,k) row of 1024.
// lane: w = lane&31, half = lane>>5 (16 h each), combine halves via shfl_xor 32.
__global__ __launch_bounds__(256) void k1b_softmax(
    const float* __restrict__ feat, u16* __restrict__ am)
{
  const int tid = threadIdx.x, lane = tid & 63, wv = tid >> 6;
  const int rid = blockIdx.x * 4 + wv;         // rid = b*64 + k
  const float* f = feat + ((size_t)rid << 10);
  u16* ar = am + ((size_t)rid << 10);
  const int w = lane & 31, half = lane >> 5;
  const int base = w + half * 512;
  float v[16];
  float m = -1e30f;
#pragma unroll
  for (int i = 0; i < 16; i++) { v[i] = f[base + i * 32]; m = fmaxf(m, v[i]); }
  m = fmaxf(m, __shfl_xor(m, 32));
  float s = 0.f;
#pragma unroll
  for (int i = 0; i < 16; i++) { v[i] = __expf(v[i] - m); s += v[i]; }
  s += __shfl_xor(s, 32);
  const float inv = 1.0f / s;
#pragma unroll
  for (int i = 0; i < 16; i++) ar[base + i * 32] = bf1(v[i] * inv);
}

// ---------------- K2: aggregation GEMM + fused normalize (no LDS) ----------------
// grid 512 = (dt 8)*(b 64); block 256 = 4 waves; wave: 64k x 16d, Kdim = n = 1024.
// Sum_n a[k][n] = 32 exactly (softmax cols sum to 1) -> fold to -32*c.
__global__ __launch_bounds__(256, 2) void k2_aggregate(
    const float* __restrict__ x, const u16* __restrict__ am,
    const float* __restrict__ cc, float* __restrict__ yw)
{
  const int blk = blockIdx.x;
  const int b = blk & 63, dt = blk >> 6;      // XCD = b%8: 8 dt-blocks share a[b] in L2
  const int tid = threadIdx.x, lane = tid & 63, wv = tid >> 6;
  const int row = lane & 15, q = lane >> 4;
  const int drow = dt * 64 + wv * 16 + row;
  const float* xb = x + ((size_t)b << 19);
  const u16* ab = am + ((size_t)b << 16);

  f32x4 acc[4];
#pragma unroll
  for (int mt = 0; mt < 4; mt++) acc[mt] = (f32x4){0.f, 0.f, 0.f, 0.f};

#pragma unroll 2
  for (int n0 = 0; n0 < 1024; n0 += 32) {
    short8 bfr;
    {  // B: x[drow][n0+q*8 ..+7] f32 -> bf16
      const float* px = xb + (size_t)drow * 1024 + n0 + q * 8;
      f32x4 g0 = *(const f32x4*)px;
      f32x4 g1 = *(const f32x4*)(px + 4);
      S8u t;
      t.q[0] = pk2(g0[0], g0[1]); t.q[1] = pk2(g0[2], g0[3]);
      t.q[2] = pk2(g1[0], g1[1]); t.q[3] = pk2(g1[2], g1[3]);
      bfr = t.s;
    }
#pragma unroll
    for (int mt = 0; mt < 4; mt++) {  // A: a[mt*16+row][n0+q*8], bf16 direct 16B
      short8 af = *(const short8*)(ab + (mt * 16 + row) * 1024 + n0 + q * 8);
      acc[mt] = __builtin_amdgcn_mfma_f32_16x16x32_bf16(af, bfr, acc[mt], 0, 0, 0);
    }
  }
  // epilogue: lane holds 16 k's for d = dcol; norm over k is wave-local (4 quads)
  const int dcol = dt * 64 + wv * 16 + row;
  float v[16]; float ss = 0.f;
#pragma unroll
  for (int mt = 0; mt < 4; mt++)
#pragma unroll
    for (int r = 0; r < 4; r++) {
      const int k = mt * 16 + q * 4 + r;
      const float t = acc[mt][r] - 32.0f * cc[k * 512 + dcol];
      v[mt * 4 + r] = t; ss += t * t;
    }
  ss += __shfl_xor(ss, 16);
  ss += __shfl_xor(ss, 32);
  const float rn = 1.0f / fmaxf(sqrtf(ss), 1e-12f);  // 2nd normalize is identity
  float* yb = yw + ((size_t)b << 15) + dcol;
#pragma unroll
  for (int mt = 0; mt < 4; mt++)
#pragma unroll
    for (int r = 0; r < 4; r++)
      yb[(size_t)(mt * 16 + q * 4 + r) << 9] = v[mt * 4 + r] * rn;
}

// ---------------- K3: (B,K,D) -> (D,K,B) ----------------
__global__ __launch_bounds__(256) void k3_transpose(
    const float* __restrict__ yw, float* __restrict__ out)
{
  const int blk = blockIdx.x;
  const int k = blk & 63;
  const int dt = blk >> 6;
  const int d0 = dt * 64;
  const int tid = threadIdx.x;
  __shared__ float T[64][68];
  {
    const int bl = tid >> 2, seg = tid & 3;
    const float* src = yw + (size_t)bl * 32768 + k * 512 + d0 + seg * 16;
#pragma unroll
    for (int i = 0; i < 4; i++) {
      f32x4 v = *(const f32x4*)(src + i * 4);
#pragma unroll
      for (int jj = 0; jj < 4; jj++) T[seg * 16 + i * 4 + jj][bl] = v[jj];
    }
  }
  __syncthreads();
  {
    const int dl = tid >> 2, bseg = tid & 3;
    float* dst = out + (size_t)(d0 + dl) * 4096 + k * 64 + bseg * 16;
    const float* srcT = &T[dl][bseg * 16];
#pragma unroll
    for (int i = 0; i < 4; i++)
      *(f32x4*)(dst + i * 4) = *(const f32x4*)(srcT + i * 4);
  }
}

extern "C" void kernel_launch(void* const* d_in, const int* in_sizes, int n_in,
                              void* d_out, int out_size, void* d_ws, size_t ws_size,
                              hipStream_t stream) {
  const float* x = (const float*)d_in[0];
  const float* w = (const float*)d_in[1];
  const float* c = (const float*)d_in[2];
  float* out = (float*)d_out;
  float* feat = (float*)d_ws;                                    // 16 MiB f32 logits
  u16*   a_ws = (u16*)((char*)d_ws + (size_t)16 * 1024 * 1024);  //  8 MiB bf16 a
  float* yw   = (float*)((char*)d_ws + (size_t)24 * 1024 * 1024);//  8 MiB f32 (B,K,D)
  k1_features <<<dim3(512),  dim3(256), 0, stream>>>(x, w, feat);
  k1b_softmax <<<dim3(1024), dim3(256), 0, stream>>>(feat, a_ws);
  k2_aggregate<<<dim3(512),  dim3(256), 0, stream>>>(x, a_ws, c, yw);
  k3_transpose<<<dim3(512),  dim3(256), 0, stream>>>(yw, out);
}

// Round 3
// 231.917 us; speedup vs baseline: 1.1832x; 1.1832x over previous
//
#include <hip/hip_runtime.h>

// NetVladCNN: B=64, D=512, H=W=32 (N=1024), K=64
// K0 : pack w f32 -> bf16 padded LDS-image (16 d-blocks)[64 k][80 B] in ws
// K1 : feat = w @ x[b] per (b, 128n-tile). x staged via global_load_lds (async,
//      double-buffered); w frags from pre-padded bf16 image (conflict-free b128).
// K1b: softmax over H; writes a as bf16 padded image (b, n-block)[64 k][80 B]
// K2 : V = a @ x^T - 32*c; a via glds contiguous image, x via pipelined reg loads;
//      fused L2-normalize over k. -> yw (B,K,D)
// K3 : transpose -> out (D,K,B)

typedef __attribute__((ext_vector_type(8))) short short8;
typedef __attribute__((ext_vector_type(4))) float f32x4;
typedef unsigned short u16;
typedef unsigned int u32;

union S8u { u32 q[4]; short8 s; };

__device__ __forceinline__ u32 pk2(float lo, float hi) {  // RNE bf16 pair pack
  union { float f; u32 u; } a, b; a.f = lo; b.f = hi;
  u32 xl = (a.u + 0x7fffu + ((a.u >> 16) & 1u)) >> 16;
  u32 xh = (b.u + 0x7fffu + ((b.u >> 16) & 1u)) & 0xffff0000u;
  return xl | xh;
}

__device__ __forceinline__ u16 bf1(float f) {
  union { float f; u32 u; } a; a.f = f;
  return (u16)((a.u + 0x7fffu + ((a.u >> 16) & 1u)) >> 16);
}

typedef const __attribute__((address_space(1))) u32 GU32;
typedef __attribute__((address_space(3))) u32 LU32;
__device__ __forceinline__ void glds16(const void* g, void* l) {
  __builtin_amdgcn_global_load_lds((GU32*)g, (LU32*)l, 16, 0, 0);
}

// ---------------- K0: pack w into padded bf16 image ----------------
// wsw image: [i=d-block 16][k 64][40 u16] (32 data + 8 pad) = 80 KB
__global__ __launch_bounds__(256) void k0_packw(
    const float* __restrict__ w, u16* __restrict__ wsw)
{
  const int tg = blockIdx.x * 256 + threadIdx.x;   // 8192 threads
  const int dd4 = tg & 7, i = (tg >> 3) & 15, k = tg >> 7;
  f32x4 v = *(const f32x4*)(w + k * 512 + i * 32 + dd4 * 4);
  u32* dst = (u32*)(wsw + ((size_t)i * 64 + k) * 40 + dd4 * 4);
  dst[0] = pk2(v[0], v[1]);
  dst[1] = pk2(v[2], v[3]);
}

// ---------------- K1: features GEMM (glds double-buffer) ----------------
// grid 512 = (ntile 8)*(b 64); block 256 = 4 waves; block tile 64k x 128n, K=512.
__global__ __launch_bounds__(256, 2) void k1_features(
    const float* __restrict__ x, const u16* __restrict__ wsw,
    float* __restrict__ feat)
{
  const int blk = blockIdx.x;
  const int b = blk & 63, nt8 = blk >> 6;          // XCD = b%8
  const int nb = nt8 * 128;
  const int tid = threadIdx.x, lane = tid & 63, wv = tid >> 6;
  const int row = lane & 15, q = lane >> 4;

  __shared__ __align__(16) float xs[2][32][128];   // 32 KB
  __shared__ __align__(16) u16 wls[2][64][40];     // 10 KB

  const char* xbase = (const char*)(x + ((size_t)b << 19) + nb);
  const char* wbase = (const char*)wsw;
  const int dd0 = tid >> 5, cby = (tid & 31) * 16; // x glds decomposition

  f32x4 acc[4][2];
#pragma unroll
  for (int mt = 0; mt < 4; mt++)
#pragma unroll
    for (int nt = 0; nt < 2; nt++) acc[mt][nt] = (f32x4){0.f, 0.f, 0.f, 0.f};

#define STAGE1(d0, buf)                                                        \
  {                                                                            \
    char* lx = (char*)&xs[buf][0][0];                                          \
    _Pragma("unroll")                                                          \
    for (int j = 0; j < 4; j++) {                                              \
      const int dd = j * 8 + dd0;                                              \
      glds16(xbase + (size_t)((d0) + dd) * 4096 + cby,                         \
             lx + j * 4096 + tid * 16);                                        \
    }                                                                          \
    char* lw = (char*)&wls[buf][0][0];                                         \
    const char* gw = wbase + (size_t)((d0) >> 5) * 5120;                       \
    glds16(gw + tid * 16, lw + tid * 16);                                      \
    if (tid < 64) glds16(gw + 4096 + tid * 16, lw + 4096 + tid * 16);          \
  }

  STAGE1(0, 0);
  for (int i = 0; i < 16; i++) {
    const int buf = i & 1;
    __syncthreads();                        // drains glds for buf (vmcnt(0))
    if (i < 15) STAGE1((i + 1) * 32, buf ^ 1);

    short8 af[4];
#pragma unroll
    for (int mt = 0; mt < 4; mt++)
      af[mt] = *(const short8*)&wls[buf][mt * 16 + row][q * 8];
    short8 bfv[2];
#pragma unroll
    for (int nt = 0; nt < 2; nt++) {
      const int n = wv * 32 + nt * 16 + row;
      const int d8 = q * 8;
      float v0 = xs[buf][d8 + 0][n], v1 = xs[buf][d8 + 1][n];
      float v2 = xs[buf][d8 + 2][n], v3 = xs[buf][d8 + 3][n];
      float v4 = xs[buf][d8 + 4][n], v5 = xs[buf][d8 + 5][n];
      float v6 = xs[buf][d8 + 6][n], v7 = xs[buf][d8 + 7][n];
      S8u t;
      t.q[0] = pk2(v0, v1); t.q[1] = pk2(v2, v3);
      t.q[2] = pk2(v4, v5); t.q[3] = pk2(v6, v7);
      bfv[nt] = t.s;
    }
#pragma unroll
    for (int nt = 0; nt < 2; nt++)
#pragma unroll
      for (int mt = 0; mt < 4; mt++)
        acc[mt][nt] = __builtin_amdgcn_mfma_f32_16x16x32_bf16(af[mt], bfv[nt], acc[mt][nt], 0, 0, 0);
  }
#undef STAGE1

  float* fb = feat + ((size_t)b << 16);
  const int nbw = nb + wv * 32;
#pragma unroll
  for (int mt = 0; mt < 4; mt++)
#pragma unroll
    for (int nt = 0; nt < 2; nt++)
#pragma unroll
      for (int r = 0; r < 4; r++)   // C layout: col=lane&15, row=q*4+r
        fb[(mt * 16 + q * 4 + r) * 1024 + nbw + nt * 16 + row] = acc[mt][nt][r];
}

// ---------------- K1b: softmax over H -> padded a image ----------------
// apad image: [b][h=n-block 32][k 64][40 u16]
__global__ __launch_bounds__(256) void k1b_softmax(
    const float* __restrict__ feat, u16* __restrict__ apad)
{
  const int tid = threadIdx.x, lane = tid & 63, wv = tid >> 6;
  const int rid = blockIdx.x * 4 + wv;         // rid = b*64 + k
  const int b = rid >> 6, k = rid & 63;
  const float* f = feat + ((size_t)rid << 10);
  const int w = lane & 31, half = lane >> 5;
  const int base = w + half * 512;
  float v[16];
  float m = -1e30f;
#pragma unroll
  for (int i = 0; i < 16; i++) { v[i] = f[base + i * 32]; m = fmaxf(m, v[i]); }
  m = fmaxf(m, __shfl_xor(m, 32));
  float s = 0.f;
#pragma unroll
  for (int i = 0; i < 16; i++) { v[i] = __expf(v[i] - m); s += v[i]; }
  s += __shfl_xor(s, 32);
  const float inv = 1.0f / s;
#pragma unroll
  for (int i = 0; i < 16; i++) {
    const int h = half * 16 + i;
    apad[((size_t)(b * 32 + h) * 64 + k) * 40 + w] = bf1(v[i] * inv);
  }
}

// ---------------- K2: aggregation + fused normalize ----------------
// grid 512 = (dt 8)*(b 64); block 256 = 4 waves; wave: 64k x 16d; 32 n-iters.
__global__ __launch_bounds__(256, 2) void k2_aggregate(
    const float* __restrict__ x, const u16* __restrict__ apad,
    const float* __restrict__ cc, float* __restrict__ yw)
{
  const int blk = blockIdx.x;
  const int b = blk & 63, dt = blk >> 6;
  const int tid = threadIdx.x, lane = tid & 63, wv = tid >> 6;
  const int row = lane & 15, q = lane >> 4;

  __shared__ __align__(16) u16 als[2][64][40];   // 10 KB

  const char* abase = (const char*)(apad + (size_t)b * 32 * 64 * 40);
  const float* px0 = x + ((size_t)b << 19) + (size_t)(dt * 64 + wv * 16 + row) * 1024 + q * 8;

#define STAGEA(i, buf)                                                         \
  {                                                                            \
    char* la = (char*)&als[buf][0][0];                                         \
    const char* ga = abase + (size_t)(i) * 5120;                               \
    glds16(ga + tid * 16, la + tid * 16);                                      \
    if (tid < 64) glds16(ga + 4096 + tid * 16, la + 4096 + tid * 16);          \
  }

  f32x4 acc[4];
#pragma unroll
  for (int mt = 0; mt < 4; mt++) acc[mt] = (f32x4){0.f, 0.f, 0.f, 0.f};

  STAGEA(0, 0);
  f32x4 c0 = *(const f32x4*)px0;
  f32x4 c1 = *(const f32x4*)(px0 + 4);
  f32x4 p0, p1;
  for (int i = 0; i < 32; i++) {
    const int buf = i & 1;
    __syncthreads();                        // drains glds + reg loads from i-1
    if (i < 31) {
      STAGEA(i + 1, buf ^ 1);
      p0 = *(const f32x4*)(px0 + (i + 1) * 32);
      p1 = *(const f32x4*)(px0 + (i + 1) * 32 + 4);
    }
    S8u t;
    t.q[0] = pk2(c0[0], c0[1]); t.q[1] = pk2(c0[2], c0[3]);
    t.q[2] = pk2(c1[0], c1[1]); t.q[3] = pk2(c1[2], c1[3]);
    const short8 bfv = t.s;
#pragma unroll
    for (int mt = 0; mt < 4; mt++) {
      short8 af = *(const short8*)&als[buf][mt * 16 + row][q * 8];
      acc[mt] = __builtin_amdgcn_mfma_f32_16x16x32_bf16(af, bfv, acc[mt], 0, 0, 0);
    }
    c0 = p0; c1 = p1;
  }
#undef STAGEA

  // epilogue: lane holds 16 k's for d = dcol; norm over k wave-local (quads)
  const int dcol = dt * 64 + wv * 16 + row;
  float v[16]; float ss = 0.f;
#pragma unroll
  for (int mt = 0; mt < 4; mt++)
#pragma unroll
    for (int r = 0; r < 4; r++) {
      const int k = mt * 16 + q * 4 + r;
      const float tv = acc[mt][r] - 32.0f * cc[k * 512 + dcol];  // Sum_n a = 32 exact
      v[mt * 4 + r] = tv; ss += tv * tv;
    }
  ss += __shfl_xor(ss, 16);
  ss += __shfl_xor(ss, 32);
  const float rn = 1.0f / fmaxf(sqrtf(ss), 1e-12f);  // 2nd normalize is identity
  float* yb = yw + ((size_t)b << 15) + dcol;
#pragma unroll
  for (int mt = 0; mt < 4; mt++)
#pragma unroll
    for (int r = 0; r < 4; r++)
      yb[(size_t)(mt * 16 + q * 4 + r) << 9] = v[mt * 4 + r] * rn;
}

// ---------------- K3: (B,K,D) -> (D,K,B) ----------------
__global__ __launch_bounds__(256) void k3_transpose(
    const float* __restrict__ yw, float* __restrict__ out)
{
  const int blk = blockIdx.x;
  const int k = blk & 63;
  const int dt = blk >> 6;
  const int d0 = dt * 64;
  const int tid = threadIdx.x;
  __shared__ float T[64][68];
  {
    const int bl = tid >> 2, seg = tid & 3;
    const float* src = yw + (size_t)bl * 32768 + k * 512 + d0 + seg * 16;
#pragma unroll
    for (int i = 0; i < 4; i++) {
      f32x4 v = *(const f32x4*)(src + i * 4);
#pragma unroll
      for (int jj = 0; jj < 4; jj++) T[seg * 16 + i * 4 + jj][bl] = v[jj];
    }
  }
  __syncthreads();
  {
    const int dl = tid >> 2, bseg = tid & 3;
    float* dst = out + (size_t)(d0 + dl) * 4096 + k * 64 + bseg * 16;
    const float* srcT = &T[dl][bseg * 16];
#pragma unroll
    for (int i = 0; i < 4; i++)
      *(f32x4*)(dst + i * 4) = *(const f32x4*)(srcT + i * 4);
  }
}

extern "C" void kernel_launch(void* const* d_in, const int* in_sizes, int n_in,
                              void* d_out, int out_size, void* d_ws, size_t ws_size,
                              hipStream_t stream) {
  const float* x = (const float*)d_in[0];
  const float* w = (const float*)d_in[1];
  const float* c = (const float*)d_in[2];
  float* out = (float*)d_out;
  char* ws = (char*)d_ws;
  float* feat = (float*)ws;                                  // 16 MiB f32 logits
  u16*   apad = (u16*)(ws + (size_t)16 * 1024 * 1024);       // 10 MiB padded a image
  float* yw   = (float*)(ws + (size_t)26 * 1024 * 1024);     //  8 MiB (B,K,D)
  u16*   wsw  = (u16*)(ws + (size_t)34 * 1024 * 1024);       // 80 KiB padded w image
  k0_packw    <<<dim3(32),   dim3(256), 0, stream>>>(w, wsw);
  k1_features <<<dim3(512),  dim3(256), 0, stream>>>(x, wsw, feat);
  k1b_softmax <<<dim3(1024), dim3(256), 0, stream>>>(feat, apad);
  k2_aggregate<<<dim3(512),  dim3(256), 0, stream>>>(x, apad, c, yw);
  k3_transpose<<<dim3(512),  dim3(256), 0, stream>>>(yw, out);
}